// Round 1
// baseline (34.817 us; speedup 1.0000x reference)
//
#include <hip/hip_runtime.h>

typedef __attribute__((ext_vector_type(8))) _Float16 half8;
typedef __attribute__((ext_vector_type(4))) float f32x4;

// ---- constants from the reference ----
#define COS_M 0.98006657784124163f
#define SIN_M 0.19866933079506122f
#define TH_C  (-0.98006657784124163f)
#define MM_C  0.039733866159012244f
#define S_OVER_TEMP (10.0f / 0.07f)

// monotone-in-c transform: c -> S*phi(c)/TEMP
__device__ inline float xform(float c) {
  float s2 = fmaxf(1.0f - c * c, 0.0f);
  float sn = sqrtf(s2);
  float phi = c * COS_M - sn * SIN_M;
  float out = (c - TH_C > 0.0f) ? phi : (c - MM_C);
  return out * S_OVER_TEMP;
}

// ---------------- K1: cf = l2norm rows of concat(views) -> f16 ----------------
__global__ __launch_bounds__(64) void k_normalize(const float* __restrict__ feats,
                                                  _Float16* __restrict__ cfn) {
  const int i = blockIdx.x;          // row in [0, 2048)
  const int b = i & 1023, v = i >> 10;
  const float* src = feats + ((size_t)b * 2 + v) * 192;
  const int t = threadIdx.x;
  float x0 = src[t], x1 = src[t + 64], x2 = src[t + 128];
  float ss = x0 * x0 + x1 * x1 + x2 * x2;
#pragma unroll
  for (int o = 32; o; o >>= 1) ss += __shfl_down(ss, o);
  ss = __shfl(ss, 0);
  float inv = 1.0f / fmaxf(sqrtf(ss), 1e-12f);
  _Float16* dst = cfn + (size_t)i * 192;
  dst[t]       = (_Float16)(x0 * inv);
  dst[t + 64]  = (_Float16)(x1 * inv);
  dst[t + 128] = (_Float16)(x2 * inv);
}

// ---------------- K2: G = cfn * cfn^T  (2048x2048 f32), MFMA f16 ----------------
// 128x128 tile per block, 4 waves (2x2), each wave 64x64 = 4x4 frags of 16x16.
__global__ __launch_bounds__(256) void k_gemm(const _Float16* __restrict__ cfn,
                                              float* __restrict__ G) {
  __shared__ _Float16 la[128 * 200];   // row stride 200 (400B) -> 2-way bank alias (free)
  __shared__ _Float16 lb[128 * 200];
  const int bm = blockIdx.x, bn = blockIdx.y;
  const uint4* srcA = (const uint4*)(cfn + (size_t)bm * 128 * 192);
  const uint4* srcB = (const uint4*)(cfn + (size_t)bn * 128 * 192);
  for (int idx = threadIdx.x; idx < 3072; idx += 256) {  // 128 rows * 24 uint4/row
    int r = idx / 24, c = idx - r * 24;
    *(uint4*)&la[r * 200 + c * 8] = srcA[idx];
    *(uint4*)&lb[r * 200 + c * 8] = srcB[idx];
  }
  __syncthreads();

  const int lane = threadIdx.x & 63;
  const int w = threadIdx.x >> 6;
  const int wr = w >> 1, wc = w & 1;   // 2x2 wave grid, 64x64 each
  const int lr = lane & 15, kg = lane >> 4;

  f32x4 acc[4][4];
#pragma unroll
  for (int m = 0; m < 4; ++m)
#pragma unroll
    for (int n = 0; n < 4; ++n) acc[m][n] = (f32x4){0.f, 0.f, 0.f, 0.f};

#pragma unroll
  for (int kc = 0; kc < 6; ++kc) {     // K = 192 = 6 * 32
    half8 af[4], bfr[4];
    const int koff = kc * 32 + kg * 8;
#pragma unroll
    for (int m = 0; m < 4; ++m)
      af[m] = *(const half8*)&la[(wr * 64 + m * 16 + lr) * 200 + koff];
#pragma unroll
    for (int n = 0; n < 4; ++n)
      bfr[n] = *(const half8*)&lb[(wc * 64 + n * 16 + lr) * 200 + koff];
#pragma unroll
    for (int m = 0; m < 4; ++m)
#pragma unroll
      for (int n = 0; n < 4; ++n)
        acc[m][n] = __builtin_amdgcn_mfma_f32_16x16x32_f16(af[m], bfr[n], acc[m][n], 0, 0, 0);
  }

  const int rb = bm * 128 + wr * 64;
  const int cb = bn * 128 + wc * 64;
#pragma unroll
  for (int m = 0; m < 4; ++m)
#pragma unroll
    for (int n = 0; n < 4; ++n) {
      const int r0 = rb + m * 16 + kg * 4;   // C/D: col=lane&15, row=(lane>>4)*4+e
      const int c0 = cb + n * 16 + lr;
#pragma unroll
      for (int e = 0; e < 4; ++e)
        G[(size_t)(r0 + e) * 2048 + c0] = acc[m][n][e];
    }
}

// ---------------- K3: per-row stats -> per-row loss ----------------
// row i: invnorm over 2048 dots; M = xform(gmax*invn); then
// expsum = sum_{j!=i} exp(adc_j - M); psum = sum_{mask} (adc_j - M); cnt.
__global__ __launch_bounds__(256) void k_rowstats(const float* __restrict__ G,
                                                  const int* __restrict__ labels,
                                                  float* __restrict__ lossv) {
  const int i = blockIdx.x;
  const int t = threadIdx.x;
  const int lane = t & 63, w = t >> 6;
  const float4* row = (const float4*)(G + (size_t)i * 2048);
  float4 v0 = row[t];        // j = 4t .. 4t+3
  float4 v1 = row[t + 256];  // j = 1024+4t .. 1024+4t+3
  float gv[8] = {v0.x, v0.y, v0.z, v0.w, v1.x, v1.y, v1.z, v1.w};

  float ss = 0.f, mx = -3.4e38f;
#pragma unroll
  for (int u = 0; u < 8; ++u) { ss += gv[u] * gv[u]; mx = fmaxf(mx, gv[u]); }
#pragma unroll
  for (int o = 32; o; o >>= 1) {
    ss += __shfl_down(ss, o);
    mx = fmaxf(mx, __shfl_down(mx, o));
  }
  __shared__ float s4[4], m4[4];
  if (lane == 0) { s4[w] = ss; m4[w] = mx; }
  __syncthreads();
  const float sst = s4[0] + s4[1] + s4[2] + s4[3];
  const float gmax = fmaxf(fmaxf(m4[0], m4[1]), fmaxf(m4[2], m4[3]));
  const float invn = 1.0f / fmaxf(sqrtf(sst), 1e-12f);
  const float Mst = xform(gmax * invn);   // loss is invariant to stabilizer choice

  const int4 lab = ((const int4*)labels)[t];
  const int labs[4] = {lab.x, lab.y, lab.z, lab.w};
  const int mylab = labels[i & 1023];

  float es = 0.f, ps = 0.f, cn = 0.f;
#pragma unroll
  for (int u = 0; u < 8; ++u) {
    const int j = (t << 2) + (u & 3) + ((u >> 2) << 10);
    const float l = xform(gv[u] * invn) - Mst;
    if (j != i) {
      es += expf(l);
      if (labs[u & 3] == mylab) { ps += l; cn += 1.f; }
    }
  }
#pragma unroll
  for (int o = 32; o; o >>= 1) {
    es += __shfl_down(es, o);
    ps += __shfl_down(ps, o);
    cn += __shfl_down(cn, o);
  }
  __shared__ float e4[4], p4[4], c4[4];
  if (lane == 0) { e4[w] = es; p4[w] = ps; c4[w] = cn; }
  __syncthreads();
  if (t == 0) {
    const float E = e4[0] + e4[1] + e4[2] + e4[3];
    const float P = p4[0] + p4[1] + p4[2] + p4[3];
    const float C = c4[0] + c4[1] + c4[2] + c4[3];
    lossv[i] = -(P / C - logf(E));
  }
}

// ---------------- K4: mean over 2048 rows -> scalar ----------------
__global__ __launch_bounds__(256) void k_final(const float* __restrict__ lossv,
                                               float* __restrict__ out) {
  const int t = threadIdx.x;
  float s = 0.f;
  for (int j = t; j < 2048; j += 256) s += lossv[j];
#pragma unroll
  for (int o = 32; o; o >>= 1) s += __shfl_down(s, o);
  __shared__ float r4[4];
  if ((t & 63) == 0) r4[t >> 6] = s;
  __syncthreads();
  if (t == 0) out[0] = (r4[0] + r4[1] + r4[2] + r4[3]) * (1.0f / 2048.0f);
}

extern "C" void kernel_launch(void* const* d_in, const int* in_sizes, int n_in,
                              void* d_out, int out_size, void* d_ws, size_t ws_size,
                              hipStream_t stream) {
  const float* feats = (const float*)d_in[0];
  const int* labels = (const int*)d_in[1];
  // d_in[2] (fc_w) and d_in[3] (fc_b) are dead: atten == 1.0 exactly (see theory)

  char* ws = (char*)d_ws;
  _Float16* cfn = (_Float16*)ws;                        // 2048*192*2   = 786432 B
  float* G      = (float*)(ws + 786432);                // 2048*2048*4  = 16 MiB
  float* lossv  = (float*)(ws + 786432 + 16777216);     // 2048*4       = 8 KiB

  k_normalize<<<2048, 64, 0, stream>>>(feats, cfn);
  dim3 g2(16, 16);
  k_gemm<<<g2, 256, 0, stream>>>(cfn, G);
  k_rowstats<<<2048, 256, 0, stream>>>(G, labels, lossv);
  k_final<<<1, 256, 0, stream>>>(lossv, (float*)d_out);
}